// Round 1
// baseline (293.056 us; speedup 1.0000x reference)
//
#include <hip/hip_runtime.h>
#include <hip/hip_bf16.h>

typedef float f32x4 __attribute__((ext_vector_type(4)));
typedef short s16x8 __attribute__((ext_vector_type(8)));

#define DIST_SCALE 25.0f

__device__ __forceinline__ unsigned short f2b(float f) {
  union { float f; unsigned u; } v; v.f = f;
  unsigned r = v.u + 0x7fffu + ((v.u >> 16) & 1u);
  return (unsigned short)(r >> 16);
}

// swizzled byte offsets (write and read must match)
__device__ __forceinline__ int swzH(int m, int kbyte) {   // H: [128][128] bf16, 256B row
  return (m * 256 + kbyte) ^ ((m & 15) << 4);
}
__device__ __forceinline__ int swzA(int m, int cbyte) {   // A0: [128][32] bf16, 64B row
  return (m * 64 + cbyte) ^ ((m & 3) << 4);
}

__global__ void prep_weights(const float* __restrict__ W1, const float* __restrict__ W2,
                             const float* __restrict__ W3, unsigned short* __restrict__ ws) {
  int t = blockIdx.x * 256 + threadIdx.x;
  int stride = gridDim.x * 256;
  // W1aT[n][k] (k padded 27->32)
  for (int i = t; i < 128 * 32; i += stride) {
    int n = i >> 5, k = i & 31;
    ws[i] = (k < 27) ? f2b(W1[k * 128 + n]) : (unsigned short)0;
  }
  unsigned short* w2t = ws + 4096;
  for (int i = t; i < 128 * 128; i += stride) {
    int n = i >> 7, k = i & 127;
    w2t[i] = f2b(W2[k * 128 + n]);
  }
  unsigned short* w3t = ws + 4096 + 16384;   // W3T[n(16 pad)][k(128)]
  for (int i = t; i < 16 * 128; i += stride) {
    int n = i >> 7, k = i & 127;
    w3t[i] = (n < 3) ? f2b(W3[k * 3 + n]) : (unsigned short)0;
  }
}

__global__ __launch_bounds__(256) void nerf_main(
    const float* __restrict__ dens, const float* __restrict__ app,
    const float* __restrict__ vdirs, const float* __restrict__ dists,
    const float* __restrict__ W1, const float* __restrict__ b1,
    const float* __restrict__ b2v, const float* __restrict__ b3v,
    const unsigned short* __restrict__ wsb, float* __restrict__ out) {
  __shared__ unsigned short A0[128 * 32];
  __shared__ unsigned short H[128 * 128];
  __shared__ float wbuf[256];
  __shared__ float hcbuf[128];
  __shared__ float featbuf[40];
  __shared__ float red[4][16];

  const int t = threadIdx.x;
  const int lane = t & 63;
  const int wv = t >> 6;
  const int r = blockIdx.x;

  const unsigned short* W1aT = wsb;
  const unsigned short* W2T = wsb + 4096;
  const unsigned short* W3T = wsb + 4096 + 16384;

  // ---------------- prologue ----------------
  if (t < 39) {   // view-dir features: [vd(3), sin(18), cos(18)] (c-major, k-minor)
    float val;
    if (t < 3) val = vdirs[r * 3 + t];
    else {
      int jj = t - 3;
      int trig = jj / 18;
      int rem = jj % 18;
      int c = rem / 6, k = rem % 6;
      float v = vdirs[r * 3 + c] * (float)(1 << k);
      val = trig ? cosf(v) : sinf(v);
    }
    featbuf[t] = val;
  }
  // zero A0 pad cols (27..31) once
  for (int i = t; i < 128 * 5; i += 256) {
    int s = i / 5, c = 27 + i % 5;
    *(unsigned short*)((char*)A0 + swzA(s, c * 2)) = 0;
  }
  // transmittance/weight scan (wave 0, 4 samples/lane)
  if (wv == 0) {
    const float4 dv = *(const float4*)(dens + (size_t)r * 256 + lane * 4);
    const float4 tv = *(const float4*)(dists + (size_t)r * 256 + lane * 4);
    float f[4], al[4];
    float dl[4] = {dv.x, dv.y, dv.z, dv.w};
    float tl[4] = {tv.x, tv.y, tv.z, tv.w};
    float p = 1.0f;
#pragma unroll
    for (int q = 0; q < 4; ++q) {
      float sg = fmaxf(dl[q], 0.0f);
      float e = __expf(-sg * tl[q] * DIST_SCALE);
      al[q] = 1.0f - e;
      f[q] = e + 1e-10f;
      p *= f[q];
    }
    float P = p;
#pragma unroll
    for (int dlt = 1; dlt < 64; dlt <<= 1) {
      float v = __shfl_up(P, dlt, 64);
      if (lane >= dlt) P *= v;
    }
    float E = __shfl_up(P, 1, 64);
    if (lane == 0) E = 1.0f;
    float tr = E;
#pragma unroll
    for (int q = 0; q < 4; ++q) { wbuf[lane * 4 + q] = al[q] * tr; tr *= f[q]; }
  }
  __syncthreads();
  // per-ray folded layer-1 bias: h1c = b1 + vd_feats @ W1[27:66]
  if (t < 128) {
    float s = b1[t];
    for (int j = 0; j < 39; ++j) s += featbuf[j] * W1[(27 + j) * 128 + t];
    hcbuf[t] = s;
  }
  __syncthreads();

  const int mb = wv * 32;        // wave-private row base within chunk
  const int cidx = lane & 15;    // N-col within tile / M-row for A frags
  const int kg = lane >> 4;      // k-group
  float pacc = 0.0f;
  const float b3c = (cidx < 3) ? b3v[cidx] : 0.0f;

  for (int chunk = 0; chunk < 2; ++chunk) {
    // ---- stage app -> A0 (bf16, swizzled) ----
    const float* appc = app + ((size_t)r * 256 + chunk * 128) * 27;
    for (int v4 = t; v4 < 864; v4 += 256) {
      float4 w = *(const float4*)(appc + v4 * 4);
      float wl[4] = {w.x, w.y, w.z, w.w};
      int e0 = v4 * 4;
#pragma unroll
      for (int u = 0; u < 4; ++u) {
        int e = e0 + u;
        int s = e / 27, c = e - s * 27;
        *(unsigned short*)((char*)A0 + swzA(s, c * 2)) = f2b(wl[u]);
      }
    }
    __syncthreads();

    // ---- layer 1: [128,32] @ [32,128] ----
    f32x4 acc1[2][8] = {};
    {
      s16x8 a0 = *(const s16x8*)((char*)A0 + swzA(mb + cidx, kg * 16));
      s16x8 a1 = *(const s16x8*)((char*)A0 + swzA(mb + 16 + cidx, kg * 16));
#pragma unroll
      for (int ct = 0; ct < 8; ++ct) {
        s16x8 b = *(const s16x8*)(W1aT + (ct * 16 + cidx) * 32 + kg * 8);
        acc1[0][ct] = __builtin_amdgcn_mfma_f32_16x16x32_bf16(a0, b, acc1[0][ct], 0, 0, 0);
        acc1[1][ct] = __builtin_amdgcn_mfma_f32_16x16x32_bf16(a1, b, acc1[1][ct], 0, 0, 0);
      }
    }
#pragma unroll
    for (int ct = 0; ct < 8; ++ct) {
      float hcv = hcbuf[ct * 16 + cidx];
#pragma unroll
      for (int rt = 0; rt < 2; ++rt)
#pragma unroll
        for (int i = 0; i < 4; ++i) {
          int m = mb + rt * 16 + kg * 4 + i;
          float val = fmaxf(acc1[rt][ct][i] + hcv, 0.0f);
          *(unsigned short*)((char*)H + swzH(m, (ct * 16 + cidx) * 2)) = f2b(val);
        }
    }
    __syncthreads();

    // ---- layer 2: [128,128] @ [128,128] ----
    f32x4 acc2[2][8] = {};
    for (int kk = 0; kk < 4; ++kk) {
      s16x8 a0 = *(const s16x8*)((char*)H + swzH(mb + cidx, (kk * 32 + kg * 8) * 2));
      s16x8 a1 = *(const s16x8*)((char*)H + swzH(mb + 16 + cidx, (kk * 32 + kg * 8) * 2));
#pragma unroll
      for (int ct = 0; ct < 8; ++ct) {
        s16x8 b = *(const s16x8*)(W2T + (ct * 16 + cidx) * 128 + kk * 32 + kg * 8);
        acc2[0][ct] = __builtin_amdgcn_mfma_f32_16x16x32_bf16(a0, b, acc2[0][ct], 0, 0, 0);
        acc2[1][ct] = __builtin_amdgcn_mfma_f32_16x16x32_bf16(a1, b, acc2[1][ct], 0, 0, 0);
      }
    }
    __syncthreads();
#pragma unroll
    for (int ct = 0; ct < 8; ++ct) {
      float b2s = b2v[ct * 16 + cidx];
#pragma unroll
      for (int rt = 0; rt < 2; ++rt)
#pragma unroll
        for (int i = 0; i < 4; ++i) {
          int m = mb + rt * 16 + kg * 4 + i;
          float val = fmaxf(acc2[rt][ct][i] + b2s, 0.0f);
          *(unsigned short*)((char*)H + swzH(m, (ct * 16 + cidx) * 2)) = f2b(val);
        }
    }
    __syncthreads();

    // ---- layer 3: [128,128] @ [128,16pad] + composite ----
    f32x4 acc3[2] = {};
#pragma unroll
    for (int kk = 0; kk < 4; ++kk) {
      s16x8 a0 = *(const s16x8*)((char*)H + swzH(mb + cidx, (kk * 32 + kg * 8) * 2));
      s16x8 a1 = *(const s16x8*)((char*)H + swzH(mb + 16 + cidx, (kk * 32 + kg * 8) * 2));
      s16x8 b = *(const s16x8*)(W3T + cidx * 128 + kk * 32 + kg * 8);
      acc3[0] = __builtin_amdgcn_mfma_f32_16x16x32_bf16(a0, b, acc3[0], 0, 0, 0);
      acc3[1] = __builtin_amdgcn_mfma_f32_16x16x32_bf16(a1, b, acc3[1], 0, 0, 0);
    }
#pragma unroll
    for (int rt = 0; rt < 2; ++rt)
#pragma unroll
      for (int i = 0; i < 4; ++i) {
        int m = mb + rt * 16 + kg * 4 + i;
        float w = wbuf[chunk * 128 + m];
        float x = acc3[rt][i] + b3c;
        if (cidx < 3) pacc += w / (1.0f + __expf(-x));
        else if (cidx == 3) pacc += w;   // free acc_map at padded col 3
      }
    __syncthreads();   // before next chunk restages A0 / overwrites H
  }

  // ---------------- final reduce + composite ----------------
  pacc += __shfl_xor(pacc, 16, 64);
  pacc += __shfl_xor(pacc, 32, 64);
  if (lane < 16) red[wv][lane] = pacc;
  __syncthreads();
  if (t < 4) red[0][t] = red[0][t] + red[1][t] + red[2][t] + red[3][t];
  __syncthreads();
  if (t < 3) {
    float v = red[0][t] + 1.0f - red[0][3];
    out[r * 3 + t] = fminf(fmaxf(v, 0.0f), 1.0f);
  }
}

extern "C" void kernel_launch(void* const* d_in, const int* in_sizes, int n_in,
                              void* d_out, int out_size, void* d_ws, size_t ws_size,
                              hipStream_t stream) {
  const float* dens = (const float*)d_in[0];
  const float* app  = (const float*)d_in[1];
  const float* vd   = (const float*)d_in[2];
  const float* dist = (const float*)d_in[3];
  const float* W1   = (const float*)d_in[4];
  const float* b1   = (const float*)d_in[5];
  const float* W2   = (const float*)d_in[6];
  const float* b2   = (const float*)d_in[7];
  const float* W3   = (const float*)d_in[8];
  const float* b3   = (const float*)d_in[9];
  unsigned short* wsb = (unsigned short*)d_ws;

  prep_weights<<<32, 256, 0, stream>>>(W1, W2, W3, wsb);
  nerf_main<<<4096, 256, 0, stream>>>(dens, app, vd, dist, W1, b1, b2, b3, wsb, (float*)d_out);
}

// Round 2
// 255.986 us; speedup vs baseline: 1.1448x; 1.1448x over previous
//
#include <hip/hip_runtime.h>
#include <hip/hip_bf16.h>

typedef float f32x4 __attribute__((ext_vector_type(4)));
typedef short s16x8 __attribute__((ext_vector_type(8)));

#define DIST_SCALE 25.0f

__device__ __forceinline__ unsigned short f2b(float f) {
  union { float f; unsigned u; } v; v.f = f;
  unsigned r = v.u + 0x7fffu + ((v.u >> 16) & 1u);
  return (unsigned short)(r >> 16);
}

// swizzled byte offsets within a WAVE-PRIVATE slice (write and read must match)
__device__ __forceinline__ int swzH(int m, int kbyte) {   // H slice: [32][128] bf16, 256B row
  return (m * 256 + kbyte) ^ ((m & 15) << 4);
}
__device__ __forceinline__ int swzA(int m, int cbyte) {   // A slice: [32][32] bf16, 64B row
  return (m * 64 + cbyte) ^ ((m & 3) << 4);
}

__global__ void prep_weights(const float* __restrict__ W1, const float* __restrict__ W2,
                             const float* __restrict__ W3, unsigned short* __restrict__ ws) {
  int t = blockIdx.x * 256 + threadIdx.x;
  int stride = gridDim.x * 256;
  // W1aT[n][k] (k padded 27->32)
  for (int i = t; i < 128 * 32; i += stride) {
    int n = i >> 5, k = i & 31;
    ws[i] = (k < 27) ? f2b(W1[k * 128 + n]) : (unsigned short)0;
  }
  unsigned short* w2t = ws + 4096;
  for (int i = t; i < 128 * 128; i += stride) {
    int n = i >> 7, k = i & 127;
    w2t[i] = f2b(W2[k * 128 + n]);
  }
  unsigned short* w3t = ws + 4096 + 16384;   // W3T[n(16 pad)][k(128)]
  for (int i = t; i < 16 * 128; i += stride) {
    int n = i >> 7, k = i & 127;
    w3t[i] = (n < 3) ? f2b(W3[k * 3 + n]) : (unsigned short)0;
  }
}

__global__ __launch_bounds__(256) void nerf_main(
    const float* __restrict__ dens, const float* __restrict__ app,
    const float* __restrict__ vdirs, const float* __restrict__ dists,
    const float* __restrict__ W1, const float* __restrict__ b1,
    const float* __restrict__ b2v, const float* __restrict__ b3v,
    const unsigned short* __restrict__ wsb, float* __restrict__ out) {
  __shared__ unsigned short A0[4][32 * 32];   // wave-private slices
  __shared__ unsigned short H[4][32 * 128];   // wave-private slices
  __shared__ float wbuf[256];
  __shared__ float hcbuf[128];
  __shared__ float featbuf[40];
  __shared__ float red[4][16];

  const int t = threadIdx.x;
  const int lane = t & 63;
  const int wv = t >> 6;
  const int r = blockIdx.x;

  const unsigned short* W1aT = wsb;
  const unsigned short* W2T = wsb + 4096;
  const unsigned short* W3T = wsb + 4096 + 16384;

  char* A0w = (char*)A0[wv];
  char* Hw = (char*)H[wv];

  // ---------------- prologue ----------------
  if (t < 39) {   // view-dir features: [vd(3), sin(18), cos(18)] (c-major, k-minor)
    float val;
    if (t < 3) val = vdirs[r * 3 + t];
    else {
      int jj = t - 3;
      int trig = jj / 18;
      int rem = jj % 18;
      int c = rem / 6, k = rem % 6;
      float v = vdirs[r * 3 + c] * (float)(1 << k);
      val = trig ? cosf(v) : sinf(v);
    }
    featbuf[t] = val;
  }
  // zero this wave's A pad cols (27..31) once; stage never rewrites them
  if (lane < 32) {
#pragma unroll
    for (int c = 27; c < 32; ++c)
      *(unsigned short*)(A0w + swzA(lane, c * 2)) = 0;
  }
  // transmittance/weight scan (wave 0, 4 samples/lane)
  if (wv == 0) {
    const float4 dv = *(const float4*)(dens + (size_t)r * 256 + lane * 4);
    const float4 tv = *(const float4*)(dists + (size_t)r * 256 + lane * 4);
    float f[4], al[4];
    float dl[4] = {dv.x, dv.y, dv.z, dv.w};
    float tl[4] = {tv.x, tv.y, tv.z, tv.w};
    float p = 1.0f;
#pragma unroll
    for (int q = 0; q < 4; ++q) {
      float sg = fmaxf(dl[q], 0.0f);
      float e = __expf(-sg * tl[q] * DIST_SCALE);
      al[q] = 1.0f - e;
      f[q] = e + 1e-10f;
      p *= f[q];
    }
    float P = p;
#pragma unroll
    for (int dlt = 1; dlt < 64; dlt <<= 1) {
      float v = __shfl_up(P, dlt, 64);
      if (lane >= dlt) P *= v;
    }
    float E = __shfl_up(P, 1, 64);
    if (lane == 0) E = 1.0f;
    float tr = E;
#pragma unroll
    for (int q = 0; q < 4; ++q) { wbuf[lane * 4 + q] = al[q] * tr; tr *= f[q]; }
  }
  __syncthreads();
  // per-ray folded layer-1 bias: h1c = b1 + vd_feats @ W1[27:66]
  if (t < 128) {
    float s = b1[t];
    for (int j = 0; j < 39; ++j) s += featbuf[j] * W1[(27 + j) * 128 + t];
    hcbuf[t] = s;
  }
  __syncthreads();
  // ---- from here on: NO barriers until the final reduce (all state wave-private) ----

  const int cidx = lane & 15;    // N-col within tile / M-row for A frags
  const int kg = lane >> 4;      // k-group
  float pacc = 0.0f;
  const float b3c = (cidx < 3) ? b3v[cidx] : 0.0f;

  for (int chunk = 0; chunk < 2; ++chunk) {
    const int rowBase = chunk * 128 + wv * 32;   // this wave's 32 samples
    // ---- stage this wave's A slab -> A0w (bf16, swizzled); slab is contiguous & 16B aligned ----
    const float* slab = app + ((size_t)r * 256 + rowBase) * 27;  // 864 floats = 216 float4
    {
      float4 w0 = *(const float4*)(slab + (lane) * 4);
      float4 w1 = *(const float4*)(slab + (lane + 64) * 4);
      float4 w2 = *(const float4*)(slab + (lane + 128) * 4);
      float4 w3;
      if (lane < 24) w3 = *(const float4*)(slab + (lane + 192) * 4);
      float4 ws4[4] = {w0, w1, w2, w3};
#pragma unroll
      for (int k = 0; k < 4; ++k) {
        if (k == 3 && lane >= 24) break;
        int e0 = (lane + 64 * k) * 4;
        float wl[4] = {ws4[k].x, ws4[k].y, ws4[k].z, ws4[k].w};
#pragma unroll
        for (int u = 0; u < 4; ++u) {
          unsigned e = e0 + u;
          unsigned s = e / 27u, c = e - s * 27u;
          *(unsigned short*)(A0w + swzA(s, c * 2)) = f2b(wl[u]);
        }
      }
    }

    // ---- layer 1: [32,32] @ [32,128] ----
    f32x4 acc1[2][8] = {};
    {
      s16x8 a0 = *(const s16x8*)(A0w + swzA(cidx, kg * 16));
      s16x8 a1 = *(const s16x8*)(A0w + swzA(16 + cidx, kg * 16));
#pragma unroll
      for (int ct = 0; ct < 8; ++ct) {
        s16x8 b = *(const s16x8*)(W1aT + (ct * 16 + cidx) * 32 + kg * 8);
        acc1[0][ct] = __builtin_amdgcn_mfma_f32_16x16x32_bf16(a0, b, acc1[0][ct], 0, 0, 0);
        acc1[1][ct] = __builtin_amdgcn_mfma_f32_16x16x32_bf16(a1, b, acc1[1][ct], 0, 0, 0);
      }
    }
#pragma unroll
    for (int ct = 0; ct < 8; ++ct) {
      float hcv = hcbuf[ct * 16 + cidx];
#pragma unroll
      for (int rt = 0; rt < 2; ++rt)
#pragma unroll
        for (int i = 0; i < 4; ++i) {
          int m = rt * 16 + kg * 4 + i;
          float val = fmaxf(acc1[rt][ct][i] + hcv, 0.0f);
          *(unsigned short*)(Hw + swzH(m, (ct * 16 + cidx) * 2)) = f2b(val);
        }
    }

    // ---- layer 2: [32,128] @ [128,128] ----
    f32x4 acc2[2][8] = {};
    for (int kk = 0; kk < 4; ++kk) {
      s16x8 a0 = *(const s16x8*)(Hw + swzH(cidx, (kk * 32 + kg * 8) * 2));
      s16x8 a1 = *(const s16x8*)(Hw + swzH(16 + cidx, (kk * 32 + kg * 8) * 2));
#pragma unroll
      for (int ct = 0; ct < 8; ++ct) {
        s16x8 b = *(const s16x8*)(W2T + (ct * 16 + cidx) * 128 + kk * 32 + kg * 8);
        acc2[0][ct] = __builtin_amdgcn_mfma_f32_16x16x32_bf16(a0, b, acc2[0][ct], 0, 0, 0);
        acc2[1][ct] = __builtin_amdgcn_mfma_f32_16x16x32_bf16(a1, b, acc2[1][ct], 0, 0, 0);
      }
    }
#pragma unroll
    for (int ct = 0; ct < 8; ++ct) {
      float b2s = b2v[ct * 16 + cidx];
#pragma unroll
      for (int rt = 0; rt < 2; ++rt)
#pragma unroll
        for (int i = 0; i < 4; ++i) {
          int m = rt * 16 + kg * 4 + i;
          float val = fmaxf(acc2[rt][ct][i] + b2s, 0.0f);
          *(unsigned short*)(Hw + swzH(m, (ct * 16 + cidx) * 2)) = f2b(val);
        }
    }

    // ---- layer 3: [32,128] @ [128,16pad] + composite ----
    f32x4 acc3[2] = {};
#pragma unroll
    for (int kk = 0; kk < 4; ++kk) {
      s16x8 a0 = *(const s16x8*)(Hw + swzH(cidx, (kk * 32 + kg * 8) * 2));
      s16x8 a1 = *(const s16x8*)(Hw + swzH(16 + cidx, (kk * 32 + kg * 8) * 2));
      s16x8 b = *(const s16x8*)(W3T + cidx * 128 + kk * 32 + kg * 8);
      acc3[0] = __builtin_amdgcn_mfma_f32_16x16x32_bf16(a0, b, acc3[0], 0, 0, 0);
      acc3[1] = __builtin_amdgcn_mfma_f32_16x16x32_bf16(a1, b, acc3[1], 0, 0, 0);
    }
#pragma unroll
    for (int rt = 0; rt < 2; ++rt)
#pragma unroll
      for (int i = 0; i < 4; ++i) {
        int m = rt * 16 + kg * 4 + i;
        float w = wbuf[rowBase + m];
        float x = acc3[rt][i] + b3c;
        if (cidx < 3) pacc += w / (1.0f + __expf(-x));
        else if (cidx == 3) pacc += w;   // free acc_map at padded col 3
      }
  }

  // ---------------- final reduce + composite ----------------
  pacc += __shfl_xor(pacc, 16, 64);
  pacc += __shfl_xor(pacc, 32, 64);
  if (lane < 16) red[wv][lane] = pacc;
  __syncthreads();
  if (t < 4) red[0][t] = red[0][t] + red[1][t] + red[2][t] + red[3][t];
  __syncthreads();
  if (t < 3) {
    float v = red[0][t] + 1.0f - red[0][3];
    out[r * 3 + t] = fminf(fmaxf(v, 0.0f), 1.0f);
  }
}

extern "C" void kernel_launch(void* const* d_in, const int* in_sizes, int n_in,
                              void* d_out, int out_size, void* d_ws, size_t ws_size,
                              hipStream_t stream) {
  const float* dens = (const float*)d_in[0];
  const float* app  = (const float*)d_in[1];
  const float* vd   = (const float*)d_in[2];
  const float* dist = (const float*)d_in[3];
  const float* W1   = (const float*)d_in[4];
  const float* b1   = (const float*)d_in[5];
  const float* W2   = (const float*)d_in[6];
  const float* b2   = (const float*)d_in[7];
  const float* W3   = (const float*)d_in[8];
  const float* b3   = (const float*)d_in[9];
  unsigned short* wsb = (unsigned short*)d_ws;

  prep_weights<<<32, 256, 0, stream>>>(W1, W2, W3, wsb);
  nerf_main<<<4096, 256, 0, stream>>>(dens, app, vd, dist, W1, b1, b2, b3, wsb, (float*)d_out);
}

// Round 3
// 190.841 us; speedup vs baseline: 1.5356x; 1.3414x over previous
//
#include <hip/hip_runtime.h>
#include <hip/hip_bf16.h>

typedef float f32x4 __attribute__((ext_vector_type(4)));
typedef short s16x8 __attribute__((ext_vector_type(8)));
typedef unsigned int u32;
typedef u32 u32x2 __attribute__((ext_vector_type(2)));

#define DIST_SCALE 25.0f

__device__ __forceinline__ unsigned short f2b(float f) {
  union { float f; unsigned u; } v; v.f = f;
  unsigned r = v.u + 0x7fffu + ((v.u >> 16) & 1u);
  return (unsigned short)(r >> 16);
}

__device__ __forceinline__ u32 cvtpk(float lo, float hi) {
  u32 r;
  asm("v_cvt_pk_bf16_f32 %0, %1, %2" : "=v"(r) : "v"(lo), "v"(hi));
  return r;
}

// H slice: [32 samples][128 ch] bf16, 256B rows, XOR-swizzled
__device__ __forceinline__ int swzH(int s, int chbyte) {
  return (s * 256 + chbyte) ^ ((s & 7) << 4);
}

__global__ void prep_weights(const float* __restrict__ W1, const float* __restrict__ W2,
                             const float* __restrict__ W3, unsigned short* __restrict__ ws) {
  int t = blockIdx.x * 256 + threadIdx.x;
  int stride = gridDim.x * 256;
  // W1aT[n][k] (k padded 27->32 with ZEROS - annihilates X pad garbage)
  for (int i = t; i < 128 * 32; i += stride) {
    int n = i >> 5, k = i & 31;
    ws[i] = (k < 27) ? f2b(W1[k * 128 + n]) : (unsigned short)0;
  }
  unsigned short* w2t = ws + 4096;
  for (int i = t; i < 128 * 128; i += stride) {
    int n = i >> 7, k = i & 127;
    w2t[i] = f2b(W2[k * 128 + n]);
  }
  unsigned short* w3t = ws + 4096 + 16384;   // W3T[n(16 pad)][k(128)]
  for (int i = t; i < 16 * 128; i += stride) {
    int n = i >> 7, k = i & 127;
    w3t[i] = (n < 3) ? f2b(W3[k * 3 + n]) : (unsigned short)0;
  }
}

__global__ __launch_bounds__(256) void nerf_main(
    const float* __restrict__ dens, const float* __restrict__ app,
    const float* __restrict__ vdirs, const float* __restrict__ dists,
    const float* __restrict__ W1, const float* __restrict__ b1,
    const float* __restrict__ b2v, const float* __restrict__ b3v,
    const unsigned short* __restrict__ wsb, float* __restrict__ out) {
  __shared__ float Xf[4][872];                // wave-private f32 staging (864 + 8 pad)
  __shared__ unsigned short H[4][32 * 128];   // wave-private activations [s][ch]
  __shared__ float wbuf[256];
  __shared__ float hcbuf[128];
  __shared__ float b2s[128];
  __shared__ float featbuf[40];
  __shared__ float red[4][4];

  const int t = threadIdx.x;
  const int lane = t & 63;
  const int wv = t >> 6;
  const int r = blockIdx.x;

  const unsigned short* W1aT = wsb;
  const unsigned short* W2T = wsb + 4096;
  const unsigned short* W3T = wsb + 4096 + 16384;

  float* Xw = Xf[wv];
  char* Hw = (char*)H[wv];

  // ---------------- prologue ----------------
  if (t < 39) {   // view-dir features: [vd(3), sin(18), cos(18)]
    float val;
    if (t < 3) val = vdirs[r * 3 + t];
    else {
      int jj = t - 3;
      int trig = jj / 18;
      int rem = jj % 18;
      int c = rem / 6, k = rem % 6;
      float v = vdirs[r * 3 + c] * (float)(1 << k);
      val = trig ? cosf(v) : sinf(v);
    }
    featbuf[t] = val;
  }
  if (t >= 64 && t < 192) b2s[t - 64] = b2v[t - 64];
  if (lane < 8) Xw[864 + lane] = 0.0f;   // finite pad for s=31 k>=27 reads
  // transmittance/weight scan (wave 0, 4 samples/lane)
  if (wv == 0) {
    const float4 dv = *(const float4*)(dens + (size_t)r * 256 + lane * 4);
    const float4 tv = *(const float4*)(dists + (size_t)r * 256 + lane * 4);
    float f[4], al[4];
    float dl[4] = {dv.x, dv.y, dv.z, dv.w};
    float tl[4] = {tv.x, tv.y, tv.z, tv.w};
    float p = 1.0f;
#pragma unroll
    for (int q = 0; q < 4; ++q) {
      float sg = fmaxf(dl[q], 0.0f);
      float e = __expf(-sg * tl[q] * DIST_SCALE);
      al[q] = 1.0f - e;
      f[q] = e + 1e-10f;
      p *= f[q];
    }
    float P = p;
#pragma unroll
    for (int dlt = 1; dlt < 64; dlt <<= 1) {
      float v = __shfl_up(P, dlt, 64);
      if (lane >= dlt) P *= v;
    }
    float E = __shfl_up(P, 1, 64);
    if (lane == 0) E = 1.0f;
    float tr = E;
#pragma unroll
    for (int q = 0; q < 4; ++q) { wbuf[lane * 4 + q] = al[q] * tr; tr *= f[q]; }
  }
  __syncthreads();
  // per-ray folded layer-1 bias: h1c = b1 + vd_feats @ W1[27:66]
  if (t < 128) {
    float s = b1[t];
    for (int j = 0; j < 39; ++j) s += featbuf[j] * W1[(27 + j) * 128 + t];
    hcbuf[t] = s;
  }
  __syncthreads();
  // ---- no barriers from here until the final reduce (all state wave-private) ----

  const int cl = lane & 15;    // sample-in-tile (B col / C col); also A row
  const int kg = lane >> 4;    // k-group; C rows = kg*4+i
  float pr = 0.0f, pg = 0.0f, pb = 0.0f, pw = 0.0f;
  const float b30 = b3v[0], b31 = b3v[1], b32 = b3v[2];

  // hoist layer-3 A-frags (uniform across chunks)
  s16x8 w3f[4];
#pragma unroll
  for (int kk = 0; kk < 4; ++kk)
    w3f[kk] = *(const s16x8*)(W3T + cl * 128 + kk * 32 + kg * 8);

  for (int chunk = 0; chunk < 2; ++chunk) {
    const int rowBase = chunk * 128 + wv * 32;   // this wave's 32 samples
    const float* slab = app + ((size_t)r * 256 + rowBase) * 27;  // 864 f32, 16B aligned

    // ---- stage X as raw f32 (coalesced float4 in, ds_write_b128 out) ----
    {
      f32x4 w0 = *(const f32x4*)(slab + 4 * lane);
      f32x4 w1 = *(const f32x4*)(slab + 4 * (lane + 64));
      f32x4 w2 = *(const f32x4*)(slab + 4 * (lane + 128));
      *(f32x4*)(Xw + 4 * lane) = w0;
      *(f32x4*)(Xw + 4 * (lane + 64)) = w1;
      *(f32x4*)(Xw + 4 * (lane + 128)) = w2;
      if (lane < 24) {
        f32x4 w3 = *(const f32x4*)(slab + 4 * (lane + 192));
        *(f32x4*)(Xw + 4 * (lane + 192)) = w3;
      }
    }

    // ---- build layer-1 B-frags from Xf (stride-27: conflict-free, 27 coprime 32) ----
    s16x8 xb[2];
#pragma unroll
    for (int st = 0; st < 2; ++st) {
      const float* xr = Xw + 27 * (st * 16 + cl) + 8 * kg;  // k>=27 garbage killed by W1aT zeros
      union { u32 u[4]; s16x8 v; } ub;
#pragma unroll
      for (int q = 0; q < 4; ++q) ub.u[q] = cvtpk(xr[2 * q], xr[2 * q + 1]);
      xb[st] = ub.v;
    }

    // ---- layer 1: C1[ch][s] = W1aT @ X^T ----
    f32x4 acc1[8][2] = {};
#pragma unroll
    for (int nt = 0; nt < 8; ++nt) {
      s16x8 a = *(const s16x8*)(W1aT + (nt * 16 + cl) * 32 + kg * 8);
      acc1[nt][0] = __builtin_amdgcn_mfma_f32_16x16x32_bf16(a, xb[0], acc1[nt][0], 0, 0, 0);
      acc1[nt][1] = __builtin_amdgcn_mfma_f32_16x16x32_bf16(a, xb[1], acc1[nt][1], 0, 0, 0);
    }
#pragma unroll
    for (int nt = 0; nt < 8; ++nt) {
      f32x4 hc = *(const f32x4*)(hcbuf + nt * 16 + kg * 4);
#pragma unroll
      for (int st = 0; st < 2; ++st) {
        int s = st * 16 + cl;
        float v0 = fmaxf(acc1[nt][st][0] + hc[0], 0.0f);
        float v1 = fmaxf(acc1[nt][st][1] + hc[1], 0.0f);
        float v2 = fmaxf(acc1[nt][st][2] + hc[2], 0.0f);
        float v3 = fmaxf(acc1[nt][st][3] + hc[3], 0.0f);
        u32x2 pk = {cvtpk(v0, v1), cvtpk(v2, v3)};
        *(u32x2*)(Hw + swzH(s, (nt * 16 + kg * 4) * 2)) = pk;
      }
    }

    // ---- layer 2: C2 = W2T @ H1^T ----
    f32x4 acc2[8][2] = {};
#pragma unroll
    for (int kk = 0; kk < 4; ++kk) {
      s16x8 hb0 = *(const s16x8*)(Hw + swzH(cl, (kk * 32 + kg * 8) * 2));
      s16x8 hb1 = *(const s16x8*)(Hw + swzH(16 + cl, (kk * 32 + kg * 8) * 2));
#pragma unroll
      for (int nt = 0; nt < 8; ++nt) {
        s16x8 a = *(const s16x8*)(W2T + (nt * 16 + cl) * 128 + kk * 32 + kg * 8);
        acc2[nt][0] = __builtin_amdgcn_mfma_f32_16x16x32_bf16(a, hb0, acc2[nt][0], 0, 0, 0);
        acc2[nt][1] = __builtin_amdgcn_mfma_f32_16x16x32_bf16(a, hb1, acc2[nt][1], 0, 0, 0);
      }
    }
#pragma unroll
    for (int nt = 0; nt < 8; ++nt) {
      f32x4 bb = *(const f32x4*)(b2s + nt * 16 + kg * 4);
#pragma unroll
      for (int st = 0; st < 2; ++st) {
        int s = st * 16 + cl;
        float v0 = fmaxf(acc2[nt][st][0] + bb[0], 0.0f);
        float v1 = fmaxf(acc2[nt][st][1] + bb[1], 0.0f);
        float v2 = fmaxf(acc2[nt][st][2] + bb[2], 0.0f);
        float v3 = fmaxf(acc2[nt][st][3] + bb[3], 0.0f);
        u32x2 pk = {cvtpk(v0, v1), cvtpk(v2, v3)};
        *(u32x2*)(Hw + swzH(s, (nt * 16 + kg * 4) * 2)) = pk;
      }
    }

    // ---- layer 3: C3[rgb][s] = W3T @ H2^T + composite ----
    f32x4 acc3[2] = {};
#pragma unroll
    for (int kk = 0; kk < 4; ++kk) {
      s16x8 hb0 = *(const s16x8*)(Hw + swzH(cl, (kk * 32 + kg * 8) * 2));
      s16x8 hb1 = *(const s16x8*)(Hw + swzH(16 + cl, (kk * 32 + kg * 8) * 2));
      acc3[0] = __builtin_amdgcn_mfma_f32_16x16x32_bf16(w3f[kk], hb0, acc3[0], 0, 0, 0);
      acc3[1] = __builtin_amdgcn_mfma_f32_16x16x32_bf16(w3f[kk], hb1, acc3[1], 0, 0, 0);
    }
    if (kg == 0) {   // rows 0..3 live in kg==0 lanes
#pragma unroll
      for (int st = 0; st < 2; ++st) {
        float w = wbuf[rowBase + st * 16 + cl];
        pw += w;
        pr += w / (1.0f + __expf(-(acc3[st][0] + b30)));
        pg += w / (1.0f + __expf(-(acc3[st][1] + b31)));
        pb += w / (1.0f + __expf(-(acc3[st][2] + b32)));
      }
    }
  }

  // ---------------- final reduce + composite ----------------
  if (kg == 0) {
#pragma unroll
    for (int d = 1; d < 16; d <<= 1) {
      pr += __shfl_xor(pr, d, 64);
      pg += __shfl_xor(pg, d, 64);
      pb += __shfl_xor(pb, d, 64);
      pw += __shfl_xor(pw, d, 64);
    }
    if (lane == 0) { red[wv][0] = pr; red[wv][1] = pg; red[wv][2] = pb; red[wv][3] = pw; }
  }
  __syncthreads();
  if (t == 0) {
    float R = 0, G = 0, B = 0, W = 0;
#pragma unroll
    for (int w = 0; w < 4; ++w) { R += red[w][0]; G += red[w][1]; B += red[w][2]; W += red[w][3]; }
    float bg = 1.0f - W;
    out[r * 3 + 0] = fminf(fmaxf(R + bg, 0.0f), 1.0f);
    out[r * 3 + 1] = fminf(fmaxf(G + bg, 0.0f), 1.0f);
    out[r * 3 + 2] = fminf(fmaxf(B + bg, 0.0f), 1.0f);
  }
}

extern "C" void kernel_launch(void* const* d_in, const int* in_sizes, int n_in,
                              void* d_out, int out_size, void* d_ws, size_t ws_size,
                              hipStream_t stream) {
  const float* dens = (const float*)d_in[0];
  const float* app  = (const float*)d_in[1];
  const float* vd   = (const float*)d_in[2];
  const float* dist = (const float*)d_in[3];
  const float* W1   = (const float*)d_in[4];
  const float* b1   = (const float*)d_in[5];
  const float* W2   = (const float*)d_in[6];
  const float* b2   = (const float*)d_in[7];
  const float* W3   = (const float*)d_in[8];
  const float* b3   = (const float*)d_in[9];
  unsigned short* wsb = (unsigned short*)d_ws;

  prep_weights<<<32, 256, 0, stream>>>(W1, W2, W3, wsb);
  nerf_main<<<4096, 256, 0, stream>>>(dens, app, vd, dist, W1, b1, b2, b3, wsb, (float*)d_out);
}